// Round 3
// baseline (202.763 us; speedup 1.0000x reference)
//
#include <hip/hip_runtime.h>

#define T_ 4
#define S_ 2048
#define D_ 768
#define SD_ (S_ * D_)          // 1572864
#define TSD_ (T_ * SD_)        // 6291456
#define H_ 12
#define HD_ 64
#define PLANE_BYTES 2359296u   // 4 planes * 768 * 768 int8 per weight matrix

typedef int int32x4 __attribute__((ext_vector_type(4)));

// async global->LDS, 16B per lane; LDS dest = wave-uniform base + lane*16
__device__ __forceinline__ void cp16(unsigned char* lds, const unsigned char* g) {
    __builtin_amdgcn_global_load_lds(
        (const __attribute__((address_space(1))) unsigned int*)g,
        (__attribute__((address_space(3))) unsigned int*)lds, 16, 0, 0);
}

// Fragment order for an Mx768 int8 matrix: chunk (m>>4, k>>6) is 1024B;
// within: (k>>4 &3)*256 + (m&15)*16 + (k&15). Wave A-frag = chunk + lane*16.
__device__ __forceinline__ size_t frag_addr(int m, int d) {
    return ((size_t)(m >> 4) * 12 + (d >> 6)) * 1024 +
           (size_t)(((d >> 4) & 3) * 256 + (m & 15) * 16 + (d & 15));
}

// ---------------------------------------------------------------------------
// 0) y<4: pack weight matrix y -> B-fragment order (LDS repack, coalesced).
//    y==4, x<128: if_node over x (16 s per block) -> init spikes, frag order,
//                 LDS-staged so global writes are 1KB-contiguous per wave.
//    y==4, x==128: zero the QKb bit-presence accumulator (1536 words).
// ---------------------------------------------------------------------------
__global__ __launch_bounds__(256) void k_prep_all(const float* __restrict__ wq,
                                                  const float* __restrict__ wk,
                                                  const float* __restrict__ wv,
                                                  const float* __restrict__ wo,
                                                  const float* __restrict__ x,
                                                  unsigned char* __restrict__ Bp,
                                                  unsigned char* __restrict__ Sx,
                                                  unsigned int* __restrict__ QKp) {
    __shared__ __align__(16) unsigned char shm[50176];  // wl(4KB) | sx tile
    int tid = threadIdx.x;
    if (blockIdx.y < 4) {
        unsigned char* wl = shm;
        const float* W = (blockIdx.y == 0) ? wq : (blockIdx.y == 1) ? wk
                       : (blockIdx.y == 2) ? wv : wo;
        unsigned char* out = Bp + (size_t)blockIdx.y * PLANE_BYTES;
        int c = blockIdx.x;            // 0..575
        int kb = c % 12;
        int nbg = c / 12;
        int k_loc = tid >> 2;
        int n_base = (tid & 3) * 4;
        float4 w4 = *(const float4*)(
            W + (size_t)(kb * 64 + k_loc) * D_ + nbg * 16 + n_base);
        float wsv[4] = {w4.x, w4.y, w4.z, w4.w};
#pragma unroll
        for (int j = 0; j < 4; j++) {
            int n_loc = n_base + j;
            int u = (int)rintf(wsv[j] * 1073741824.0f);   // w * 2^30
#pragma unroll
            for (int p = 0; p < 4; p++) {
                wl[p * 1024 + (n_loc + 16 * (k_loc >> 4)) * 16 + (k_loc & 15)] =
                    (unsigned char)(u & 255);
                u = (u + 128) >> 8;                        // balanced peel
            }
        }
        __syncthreads();
        int p = tid >> 6;
        int lane = tid & 63;
        uint4 val = *(const uint4*)&wl[p * 1024 + lane * 16];
        *(uint4*)(out + (size_t)((p * 48 + nbg) * 12 + kb) * 1024 + lane * 16) =
            val;
    } else {
        if (blockIdx.x >= 128) {
            if (blockIdx.x == 128) {
                for (int i = tid; i < 1536; i += 256) QKp[i] = 0u;  // QKb 6KB
            }
            return;
        }
        // 16 s-rows per block; spikes staged in LDS [4][16][49] uint4
        // (+1 uint4 pad: read-phase lane stride 196 words == 4 mod 32 banks).
        int s0 = blockIdx.x * 16;
        uint4* sx = (uint4*)shm;
        for (int p = 0; p < 3; p++) {
            int pi = tid + p * 256;       // 0..767
            int sl = pi / 48;             // 0..15
            int dc = pi % 48;             // d-chunk of 16
            int d0 = dc * 16;
            double v[16];
#pragma unroll
            for (int j = 0; j < 16; j++) v[j] = 0.0;
#pragma unroll
            for (int t = 0; t < T_; t++) {
                union { uint4 u; unsigned char b[16]; } sp;
#pragma unroll
                for (int q = 0; q < 4; q++) {
                    float4 xt = *(const float4*)(
                        x + (size_t)t * SD_ + (size_t)(s0 + sl) * D_ + d0 +
                        q * 4);
                    float xs[4] = {xt.x, xt.y, xt.z, xt.w};
#pragma unroll
                    for (int j = 0; j < 4; j++) {
                        int jj = q * 4 + j;
                        v[jj] += (double)xs[j];
                        unsigned char ss = (v[jj] >= 1.0) ? 1 : 0;
                        sp.b[jj] = ss;
                        if (ss) v[jj] = 0.0;
                    }
                }
                sx[(t * 16 + sl) * 49 + dc] = sp.u;
            }
        }
        __syncthreads();
        // coalesced write-out: per t a contiguous 12KB frag region
#pragma unroll
        for (int j = 0; j < 12; j++) {
            int f = tid + j * 256;        // 0..3071
            int t = f / 768;
            int u = f % 768;              // uint4 index within t-region
            int sl = u & 15;
            int dc = ((u >> 6) << 2) | ((u >> 4) & 3);
            uint4 val = sx[(t * 16 + sl) * 49 + dc];
            *(uint4*)(Sx + ((size_t)(t * 128 + (s0 >> 4)) * 12) * 1024 +
                      (size_t)u * 16) = val;
        }
    }
}

// ---------------------------------------------------------------------------
// 2) i8 MFMA GEMM, exact fixed-point. B LDS-staged with BK=128 (2 k-blocks
//    per barrier, 2x32KB dbuf); A streamed from global fragment order with
//    register rotation. Optional mask: Mp = QKb presence BITS (16 copies x
//    4 t x 12 u64); prologue ORs copies and expands bits -> byte mask.
//    Tile 128M x 64N; 4 waves 2x2; wave 64M x 32N x 4 planes (128 AGPR acc).
//    NOTE (R1 post-mortem): counted-vmcnt BK=64 rewrite regressed 57->92.5us
//    (restage-after-consume narrows prefetch window to ONE kstep < L2-miss
//    latency, doubles barriers). This stage-at-iteration-start BK=128 form
//    is the verified-fast structure; FROZEN.
// ---------------------------------------------------------------------------
__global__ __launch_bounds__(256, 2) void k_gemm_i8(
    const unsigned char* __restrict__ A,   // fragment-order spikes
    const unsigned char* __restrict__ Bp,  // packed digit planes (frag order)
    const unsigned int* __restrict__ Mp,   // QKb bits or nullptr
    float* __restrict__ C0, float* __restrict__ C1, float* __restrict__ C2,
    int bzoff) {
    int z = blockIdx.z;
    const unsigned char* B = Bp + (size_t)(bzoff + z) * PLANE_BYTES;
    float* C = (z == 0) ? C0 : (z == 1) ? C1 : C2;

    __shared__ __align__(16) unsigned char bsm[2 * 32768];
    __shared__ __align__(16) unsigned int maskw[192];

    int tid = threadIdx.x;
    int lane = tid & 63;
    int w = tid >> 6;                 // wave 0..3
    int wm = w >> 1;                  // 0..1
    int wn = w & 1;                   // 0..1
    int row0 = blockIdx.x * 128;
    int tI = row0 >> 11;              // uniform t for this block
    int n0 = blockIdx.y * 64;
    int nbg0 = blockIdx.y * 4;
    int col = lane & 15;
    int quad = lane >> 4;

    int32x4 zerov = {0, 0, 0, 0};
    int32x4 acc[4][2][4];             // [mb][nb][p]
#pragma unroll
    for (int mb = 0; mb < 4; mb++)
#pragma unroll
        for (int nb = 0; nb < 2; nb++)
#pragma unroll
            for (int p = 0; p < 4; p++) acc[mb][nb][p] = zerov;

    const unsigned char* Ab =
        A + (size_t)((row0 >> 4) + wm * 4) * 12 * 1024 + lane * 16;

    // stage k-blocks 2*kb2 and 2*kb2+1 into buffer buf
    auto stageB = [&](int buf, int kb2) {
        unsigned char* bb = bsm + buf * 32768;
#pragma unroll
        for (int kk = 0; kk < 2; kk++)
#pragma unroll
            for (int qi = 0; qi < 4; qi++) {
                int q = w * 4 + qi;       // chunk id: p = q>>2, nb = q&3
                int p = q >> 2, nb = q & 3;
                cp16(bb + kk * 16384 + q * 1024,
                     B + (size_t)((p * 48 + nbg0 + nb) * 12 + 2 * kb2 + kk) *
                             1024 + lane * 16);
            }
    };

    stageB(0, 0);
    if (Mp && tid < 192) {
        // OR 16 bit-copies for this t, expand 4 bits -> 4 mask bytes {0,1}
        const unsigned long long* Qb = (const unsigned long long*)Mp;
        unsigned long long m = 0;
#pragma unroll
        for (int c = 0; c < 16; c++) m |= Qb[(c * 4 + tI) * 12 + (tid >> 4)];
        unsigned int nib =
            (unsigned int)((m >> (4 * (tid & 15))) & 0xFull);
        maskw[tid] = (nib & 1u) | ((nib & 2u) << 7) | ((nib & 4u) << 14) |
                     ((nib & 8u) << 21);
    }
    int32x4 a[2][4];
#pragma unroll
    for (int mb = 0; mb < 4; mb++)
        a[0][mb] = *(const int32x4*)(Ab + (size_t)(mb * 12) * 1024);
    __syncthreads();

    for (int kb2 = 0; kb2 < 6; kb2++) {
        int cur = kb2 & 1;
        if (kb2 < 5) stageB(1 - cur, kb2 + 1);
#pragma unroll
        for (int kbh = 0; kbh < 2; kbh++) {
            int kb = kb2 * 2 + kbh;
            if (kb < 11) {
#pragma unroll
                for (int mb = 0; mb < 4; mb++)
                    a[(kb + 1) & 1][mb] = *(const int32x4*)(
                        Ab + (size_t)(mb * 12 + kb + 1) * 1024);
            }
            int32x4 af[4];
#pragma unroll
            for (int mb = 0; mb < 4; mb++) af[mb] = a[kb & 1][mb];
            if (Mp) {
                int32x4 mv = *(const int32x4*)(
                    (const unsigned char*)maskw + kb * 64 + quad * 16);
#pragma unroll
                for (int mb = 0; mb < 4; mb++) af[mb] &= mv;
            }
            const unsigned char* bb = bsm + cur * 32768 + kbh * 16384;
#pragma unroll
            for (int p = 0; p < 4; p++)
#pragma unroll
                for (int nb = 0; nb < 2; nb++) {
                    int32x4 bf = *(const int32x4*)(
                        bb + (size_t)(p * 4 + wn * 2 + nb) * 1024 + lane * 16);
#pragma unroll
                    for (int mb = 0; mb < 4; mb++)
                        acc[mb][nb][p] = __builtin_amdgcn_mfma_i32_16x16x64_i8(
                            af[mb], bf, acc[mb][nb][p], 0, 0, 0);
                }
        }
        __syncthreads();
    }

#pragma unroll
    for (int mb = 0; mb < 4; mb++)
#pragma unroll
        for (int nb = 0; nb < 2; nb++)
#pragma unroll
            for (int r = 0; r < 4; r++) {
                // exact: digits < 2^17, products/sums exact in double
                double td = (double)acc[mb][nb][0][r]
                          + 256.0 * (double)acc[mb][nb][1][r]
                          + 65536.0 * (double)acc[mb][nb][2][r]
                          + 16777216.0 * (double)acc[mb][nb][3][r];
                float v = (float)(td * (1.0 / 1073741824.0));
                int rr = row0 + wm * 64 + mb * 16 + quad * 4 + r;
                int cc = n0 + wn * 32 + nb * 16 + col;
                C[(size_t)rr * D_ + cc] = v;
            }
}

// ---------------------------------------------------------------------------
// 3) Fused BN + IF for Q,K,V in ONE block per s. float4 loads, single merged
//    reduction (3 barriers). q&k presence: wave __ballot -> ONE u64 atomicOr
//    per wave per (t, d-range) into QKb[s%16] copies (48 atomics/block vs
//    768 before). V spikes written int8 fragment-order.
// ---------------------------------------------------------------------------
__global__ __launch_bounds__(256) void k_bnif_qk(const float* __restrict__ Qf,
                                                 const float* __restrict__ Kf,
                                                 const float* __restrict__ Vf,
                                                 unsigned char* __restrict__ Vs,
                                                 unsigned int* __restrict__ QKp) {
    int s = blockIdx.x;
    __shared__ float buf[3][T_][D_];          // 36 KB
    __shared__ double red[4][6];
    __shared__ unsigned char spkV[T_ * D_];   // 3 KB
    __shared__ double stats[3][2];            // mean, rstd per tensor

    int tid = threadIdx.x;
    int lane = tid & 63, wv = tid >> 6;
    const float* Xs[3] = {Qf, Kf, Vf};
    double sum[3] = {0.0, 0.0, 0.0}, sumsq[3] = {0.0, 0.0, 0.0};
#pragma unroll
    for (int y = 0; y < 3; y++) {
#pragma unroll
        for (int i = 0; i < 3; i++) {
            int idx = i * 256 + tid;          // 0..767 float4 chunks
            int t = idx / 192;
            int c = idx - t * 192;
            float4 v = *(const float4*)(
                Xs[y] + (size_t)t * SD_ + (size_t)s * D_ + c * 4);
            *(float4*)&buf[y][t][c * 4] = v;
            sum[y] += ((double)v.x + (double)v.y) +
                      ((double)v.z + (double)v.w);
            sumsq[y] += ((double)v.x * v.x + (double)v.y * v.y) +
                        ((double)v.z * v.z + (double)v.w * v.w);
        }
    }
#pragma unroll
    for (int off = 32; off > 0; off >>= 1) {
#pragma unroll
        for (int y = 0; y < 3; y++) {
            sum[y] += __shfl_down(sum[y], off);
            sumsq[y] += __shfl_down(sumsq[y], off);
        }
    }
    if (lane == 0) {
#pragma unroll
        for (int y = 0; y < 3; y++) {
            red[wv][y] = sum[y];
            red[wv][3 + y] = sumsq[y];
        }
    }
    __syncthreads();
    if (tid < 3) {
        double s4 = red[0][tid] + red[1][tid] + red[2][tid] + red[3][tid];
        double q4 = red[0][3 + tid] + red[1][3 + tid] + red[2][3 + tid] +
                    red[3][3 + tid];
        double mean = s4 / 3072.0;
        double var = q4 / 3072.0 - mean * mean;
        stats[tid][0] = mean;
        stats[tid][1] = 1.0 / sqrt(var + 1e-5);
    }
    __syncthreads();

    unsigned long long* QKb =
        (unsigned long long*)QKp + ((size_t)(s & 15) * 4) * 12;
#pragma unroll
    for (int i = 0; i < 3; i++) {
        int d = i * 256 + tid;
        unsigned char qs[T_], ks[T_];
#pragma unroll
        for (int y = 0; y < 3; y++) {
            double mean = stats[y][0], rstd = stats[y][1];
            double v = 0.0;
#pragma unroll
            for (int t = 0; t < T_; t++) {
                double xn = ((double)buf[y][t][d] - mean) * rstd;
                v += xn;
                unsigned char sp = (v >= 1.0) ? 1 : 0;
                if (y == 0) qs[t] = sp;
                else if (y == 1) ks[t] = sp;
                else spkV[t * D_ + d] = sp;
                if (sp) v = 0.0;
            }
        }
#pragma unroll
        for (int t = 0; t < T_; t++) {
            unsigned long long b = __ballot(qs[t] & ks[t]);
            if (lane == 0 && b) atomicOr(QKb + t * 12 + (i * 4 + wv), b);
        }
    }
    __syncthreads();

    if (tid < 192) {
        // V spikes -> fragment order (16-byte granules)
        int tt = tid / 48, gg = tid % 48;
        uint4 val = *(const uint4*)&spkV[tt * D_ + gg * 16];
        size_t dst = ((size_t)(tt * 128 + (s >> 4)) * 12 + (gg >> 2)) * 1024 +
                     (size_t)((gg & 3) * 256 + (s & 15) * 16);
        *(uint4*)(Vs + dst) = val;
    }
}

// ---------------------------------------------------------------------------
// 6) Final BatchNorm1d (fp64 stats), register-resident, float4 in/out.
// ---------------------------------------------------------------------------
__global__ __launch_bounds__(256) void k_bn_out(const float* __restrict__ Xin,
                                                float* __restrict__ out) {
    int s = blockIdx.x;
    __shared__ double red[4][2];
    __shared__ double st[2];
    int tid = threadIdx.x;
    int lane = tid & 63, wv = tid >> 6;
    float4 vv[3];
    double sum = 0.0, sumsq = 0.0;
#pragma unroll
    for (int i = 0; i < 3; i++) {
        int idx = i * 256 + tid;
        int t = idx / 192, c = idx - t * 192;
        float4 v = *(const float4*)(
            Xin + (size_t)t * SD_ + (size_t)s * D_ + c * 4);
        vv[i] = v;
        sum += ((double)v.x + (double)v.y) + ((double)v.z + (double)v.w);
        sumsq += ((double)v.x * v.x + (double)v.y * v.y) +
                 ((double)v.z * v.z + (double)v.w * v.w);
    }
#pragma unroll
    for (int off = 32; off > 0; off >>= 1) {
        sum += __shfl_down(sum, off);
        sumsq += __shfl_down(sumsq, off);
    }
    if (lane == 0) { red[wv][0] = sum; red[wv][1] = sumsq; }
    __syncthreads();
    if (tid == 0) {
        double s4 = red[0][0] + red[1][0] + red[2][0] + red[3][0];
        double q4 = red[0][1] + red[1][1] + red[2][1] + red[3][1];
        double mean = s4 / 3072.0;
        double var = q4 / 3072.0 - mean * mean;
        st[0] = mean;
        st[1] = 1.0 / sqrt(var + 1e-5);
    }
    __syncthreads();
    double mean = st[0], rstd = st[1];
#pragma unroll
    for (int i = 0; i < 3; i++) {
        int idx = i * 256 + tid;
        int t = idx / 192, c = idx - t * 192;
        float4 o;
        o.x = (float)(((double)vv[i].x - mean) * rstd);
        o.y = (float)(((double)vv[i].y - mean) * rstd);
        o.z = (float)(((double)vv[i].z - mean) * rstd);
        o.w = (float)(((double)vv[i].w - mean) * rstd);
        *(float4*)(out + (size_t)t * SD_ + (size_t)s * D_ + c * 4) = o;
    }
}

// ---------------------------------------------------------------------------
extern "C" void kernel_launch(void* const* d_in, const int* in_sizes, int n_in,
                              void* d_out, int out_size, void* d_ws,
                              size_t ws_size, hipStream_t stream) {
    const float* x  = (const float*)d_in[0];
    const float* wq = (const float*)d_in[1];
    const float* wk = (const float*)d_in[2];
    const float* wv = (const float*)d_in[3];
    const float* wo = (const float*)d_in[4];
    float* out = (float*)d_out;

    float* ws  = (float*)d_ws;
    float* Qf  = ws;                         // pre-BN Q, then GEMM2 out
    float* Kf  = ws + (size_t)TSD_;
    float* Vf  = ws + (size_t)2 * TSD_;
    unsigned int* QKp = (unsigned int*)(ws + (size_t)3 * TSD_);  // QKb bits
    unsigned char* Sx = (unsigned char*)(QKp + 12288);  // init spikes (frag)
    unsigned char* Vs = Sx + (size_t)TSD_;
    unsigned char* Bp = Vs + (size_t)TSD_;   // packed weights, 9.4 MB

    // 0) pack weights + init spikes + zero QKb
    k_prep_all<<<dim3(576, 5), 256, 0, stream>>>(wq, wk, wv, wo, x, Bp, Sx,
                                                 QKp);
    // 1) Q/K/V GEMMs (A from global frag-order, B LDS dbuf BK=128)
    k_gemm_i8<<<dim3(64, 12, 3), 256, 0, stream>>>(Sx, Bp, nullptr,
                                                   Qf, Kf, Vf, 0);
    // 2) BN + IF for Q,K,V + ballot-packed q&k presence accumulation
    k_bnif_qk<<<S_, 256, 0, stream>>>(Qf, Kf, Vf, Vs, QKp);
    // 3) out_pre = (Vs & mask) @ wo -> Qf  (bit mask OR-expanded in prologue)
    k_gemm_i8<<<dim3(64, 12, 1), 256, 0, stream>>>(Vs, Bp, QKp, Qf, Qf, Qf, 3);
    // 4) final BN -> d_out
    k_bn_out<<<S_, 256, 0, stream>>>(Qf, out);
}